// Round 2
// 692.008 us; speedup vs baseline: 1.0767x; 1.0767x over previous
//
#include <hip/hip_runtime.h>
#include <cstdint>

typedef float  f32x4  __attribute__((ext_vector_type(4)));
typedef __bf16 bf16x8 __attribute__((ext_vector_type(8)));
typedef int    i32x4  __attribute__((ext_vector_type(4)));
typedef unsigned short u16;
typedef u16 u16x4 __attribute__((ext_vector_type(4)));

#define TT 512

// ---------- helpers ----------
__device__ __forceinline__ u16 f2bf(float f) {
  unsigned u = __builtin_bit_cast(unsigned, f);
  unsigned r = u + 0x7fffu + ((u >> 16) & 1u);   // RNE
  return (u16)(r >> 16);
}
__device__ __forceinline__ float bflo(unsigned d) { return __builtin_bit_cast(float, d << 16); }
__device__ __forceinline__ float bfhi(unsigned d) { return __builtin_bit_cast(float, d & 0xffff0000u); }
__device__ __forceinline__ float rcpf(float x) { return __builtin_amdgcn_rcpf(x); }
__device__ __forceinline__ float fsig(float x) { return rcpf(1.f + __expf(-x)); }
__device__ __forceinline__ float ftanh(float x) { return 1.f - 2.f * rcpf(1.f + __expf(2.f * x)); }
__device__ __forceinline__ void gload_lds16(const u16* g, u16* l) {
  __builtin_amdgcn_global_load_lds((const __attribute__((address_space(1))) void*)(g),
                                   (__attribute__((address_space(3))) void*)(l), 16, 0, 0);
}

// ---------- prep: Wx -> bf16 transposed; Wh -> i8 per-col quant; bias sum ----------
__global__ __launch_bounds__(256) void prep_w(
    const float* __restrict__ wii, const float* __restrict__ whi,
    const float* __restrict__ wif, const float* __restrict__ whf,
    const float* __restrict__ wig, const float* __restrict__ whg,
    const float* __restrict__ wio, const float* __restrict__ who,
    const float* __restrict__ bii, const float* __restrict__ bhi,
    const float* __restrict__ bif, const float* __restrict__ bhf,
    const float* __restrict__ big_, const float* __restrict__ bhg,
    const float* __restrict__ bio, const float* __restrict__ bho,
    u16* __restrict__ Wxb, signed char* __restrict__ Whq,
    float* __restrict__ wscale, float* __restrict__ bsum) {
  __shared__ float red[256];
  int b = blockIdx.x;
  int tid = threadIdx.x;
  if (b < 1024) {                 // Wxb_t[col][d] = w_x{G}[d][h], col = G*256+h
    const float* wx[4] = {wii, wif, wig, wio};
    int G = b >> 8, h = b & 255;
    Wxb[b * 256 + tid] = f2bf(wx[G][tid * 256 + h]);
  } else if (b < 2048) {          // Whq[col][u] = quant(w_h{G}[u][h]), per-col scale
    const float* wh[4] = {whi, whf, whg, who};
    int cidx = b - 1024;
    int G = cidx >> 8, h = cidx & 255;
    float w = wh[G][tid * 256 + h];
    red[tid] = fabsf(w);
    __syncthreads();
    for (int s = 128; s > 0; s >>= 1) {
      if (tid < s) red[tid] = fmaxf(red[tid], red[tid + s]);
      __syncthreads();
    }
    float mx = red[0];
    float scale = (mx > 0.f) ? mx * (1.f / 127.f) : 1.f;
    float qf = rintf(w / scale);
    qf = fminf(127.f, fmaxf(-127.f, qf));
    Whq[cidx * 256 + tid] = (signed char)(int)qf;
    if (tid == 0) wscale[cidx] = scale * (1.f / 127.f);   // combined w-scale * h-scale
  } else {
    const float* bx[4] = {bii, bif, big_, bio};
    const float* bh[4] = {bhi, bhf, bhg, bho};
    for (int G = 0; G < 4; ++G) bsum[G * 256 + tid] = bx[G][tid] + bh[G][tid];
  }
}

// ---------- phase 1: xWp = pack(x @ Wx + b) ----------
// Fused prep_x + GEMM. 1024 wgs x 128-row strips (row = t*256+n); A strip
// (128x256) converted f32->bf16 in-kernel and held resident in LDS (64KB,
// XOR-swizzled: within-row linear byte offset o stored at o ^ ((row&7)<<4)).
// READ SIDE applies the SAME involution: row*512 + ((ko*64+q*16) ^ sw) —
// round-1 bug was adding ko*64 AFTER the XOR (carry from bit6 corrupted addr).
// bn-loop over the 8 col-tiles with double-buffered 8KB B staging
// (global_load_lds w16, stage-next-before-compute, one barrier/iter).
// Output tile-packed (MFMA C layout) identical to verified 745us version:
// xWp[(tm*64+tn)*256 + l*4 + r], lane l = q*16+c -> rows q*4+r, col c.
__global__ __launch_bounds__(256, 2) void gemm_xw(const float* __restrict__ X, const u16* __restrict__ Bt,
                                                  const float* __restrict__ bias, u16* __restrict__ xWp) {
  __shared__ u16 As[128 * 256];     // 64 KB, full-K A strip, swizzled
  __shared__ u16 Bs[2][128 * 32];   // 2 x 8 KB double buffer
  int bm = blockIdx.x;              // 0..1023
  int tid = threadIdx.x;
  int l = tid & 63, w = tid >> 6;
  int wm = w >> 1, wn = w & 1;
  int c = l & 15, q = l >> 4;

  // stage B(bn=0,ko=0) early so its latency hides under A conversion
  {
    int trow = tid >> 2, ch = tid & 3;
    gload_lds16(Bt + (size_t)trow * 256 + ch * 8, &Bs[0][0] + tid * 8);
    gload_lds16(Bt + (size_t)(trow + 64) * 256 + ch * 8, &Bs[0][0] + 2048 + tid * 8);
  }
  // stage A: 128 rows x 256 k, read x (N,T,D) f32 directly, convert, swizzle
  {
#pragma unroll 4
    for (int j = 0; j < 32; ++j) {
      int row_l = j * 4 + (tid >> 6);           // wave reads one row contiguously
      int d = (tid & 63) * 4;
      int r = bm * 128 + row_l;
      int t = r >> 8, n = r & 255;
      const float4 v = *(const float4*)(X + ((size_t)n * 512 + t) * 256 + d);
      u16x4 p;
      p[0] = f2bf(v.x); p[1] = f2bf(v.y); p[2] = f2bf(v.z); p[3] = f2bf(v.w);
      int ba = (row_l * 512 + d * 2) ^ ((row_l & 7) << 4);
      *(u16x4*)((char*)As + ba) = p;
    }
  }
  __syncthreads();

  f32x4 acc[4][4];
#pragma unroll
  for (int i = 0; i < 4; ++i)
#pragma unroll
    for (int j = 0; j < 4; ++j) acc[i][j] = (f32x4){0.f, 0.f, 0.f, 0.f};

  // per-lane A row bases; swizzle key (row&7)<<4 == (c&7)<<4 since
  // wm*64 + mt*16 ≡ 0 (mod 8). XOR applied per-ko inside the loop.
  int sw = (c & 7) << 4;
  int rowbase[4];
#pragma unroll
  for (int mt = 0; mt < 4; ++mt)
    rowbase[mt] = (wm * 64 + mt * 16 + c) * 512;

  for (int bn = 0; bn < 8; ++bn) {
#pragma unroll
    for (int ko = 0; ko < 8; ++ko) {
      int sn = bn * 8 + ko + 1;                 // stage next (bn,ko) before compute
      if (sn < 64) {
        int bnn = sn >> 3, kon = sn & 7;
        const u16* Bb = Bt + (size_t)(bnn * 128) * 256 + kon * 32;
        u16* dst = &Bs[(ko + 1) & 1][0];
        int trow = tid >> 2, ch = tid & 3;
        gload_lds16(Bb + (size_t)trow * 256 + ch * 8, dst + tid * 8);
        gload_lds16(Bb + (size_t)(trow + 64) * 256 + ch * 8, dst + 2048 + tid * 8);
      }
      bf16x8 af[4], bfr[4];
      const u16* bp = &Bs[ko & 1][0];
      int koff = (ko * 64 + q * 16) ^ sw;       // full XOR involution, matches write
#pragma unroll
      for (int mt = 0; mt < 4; ++mt)
        af[mt] = *(const bf16x8*)((const char*)As + rowbase[mt] + koff);
#pragma unroll
      for (int nt = 0; nt < 4; ++nt)
        bfr[nt] = *(const bf16x8*)(bp + (wn * 64 + nt * 16 + c) * 32 + q * 8);
#pragma unroll
      for (int mt = 0; mt < 4; ++mt)
#pragma unroll
        for (int nt = 0; nt < 4; ++nt)
          acc[mt][nt] = __builtin_amdgcn_mfma_f32_16x16x32_bf16(af[mt], bfr[nt], acc[mt][nt], 0, 0, 0);
      __syncthreads();              // vmcnt(0): next B staged; lgkm: reads done
    }
    // epilogue for this bn (identical packing to previous verified kernel)
#pragma unroll
    for (int mt = 0; mt < 4; ++mt) {
      int tm = bm * 8 + wm * 4 + mt;
#pragma unroll
      for (int nt = 0; nt < 4; ++nt) {
        int tn = bn * 8 + wn * 4 + nt;
        float bv = bias[tn * 16 + c];
        u16x4 pk;
#pragma unroll
        for (int r = 0; r < 4; ++r) pk[r] = f2bf(acc[mt][nt][r] + bv);
        *reinterpret_cast<u16x4*>(xWp + ((size_t)(tm * 64 + tn) * 256 + l * 4)) = pk;
        acc[mt][nt] = (f32x4){0.f, 0.f, 0.f, 0.f};
      }
    }
  }
}

// ---------- phase 2: recurrence, CU-local, AGPR-pinned weights ----------
// (unchanged — control for this round)
__global__ __launch_bounds__(512, 2) void lstm_rec(const signed char* __restrict__ Whq,
                                                   const float* __restrict__ wscale,
                                                   const u16* __restrict__ xWp,
                                                   float* __restrict__ out) {
  __shared__ __align__(16) signed char hb[2][576];   // 2 x (2 rows x 288B)
  int p = blockIdx.x;            // 0..127
  int xcd = p & 7, q8 = (p >> 3) & 7, tsel = p >> 6;
  int G = xcd * 2 + tsel;        // 16-row tile id; 8 co-XCD sharers
  int tid = threadIdx.x;
  int wid = tid >> 6, l = tid & 63;
  int c = l & 15, q = (l >> 4) & 3;
  int tt = q >> 1, rsel = q & 1;

  for (int i = tid; i < 288; i += 512) ((int*)hb)[i] = 0;

  // Wh i8 fragments: [gate][tt-tile][kstep] -> forced into AGPRs by asm "a" use
  i32x4 bw[4][2][4];
#pragma unroll
  for (int g = 0; g < 4; ++g)
#pragma unroll
    for (int ttl = 0; ttl < 2; ++ttl) {
      int col = g * 256 + wid * 32 + ttl * 16 + c;
#pragma unroll
      for (int ks = 0; ks < 4; ++ks)
        bw[g][ttl][ks] = *reinterpret_cast<const i32x4*>(Whq + (size_t)col * 256 + ks * 64 + q * 16);
    }
  float sc8[4];
#pragma unroll
  for (int g = 0; g < 4; ++g) sc8[g] = wscale[g * 256 + wid * 32 + tt * 16 + c];

  // xW: tile tm = t*16 + G; this wg's rows are regs {2*(q8&1), +1} of quad q8>>1
  const char* xbase = (const char*)xWp + (size_t)G * 32768;
  int xoff[4];
#pragma unroll
  for (int g = 0; g < 4; ++g) {
    int tn = g * 16 + wid * 2 + tt;
    xoff[g] = tn * 512 + (((q8 >> 1) * 16 + c) * 8) + (q8 & 1) * 4;
  }
  unsigned xw0[4], xw1[4];
#pragma unroll
  for (int g = 0; g < 4; ++g) xw0[g] = *(const unsigned*)(xbase + xoff[g]);   // t=0
  xbase += 524288;   // -> t=1

  i32x4 zacc = (i32x4){0, 0, 0, 0};
  float cs = 0.f, hh = 0.f;
  __syncthreads();

#define STEP(CUR, XW_CUR, XW_NXT)                                               \
  {                                                                             \
    _Pragma("unroll")                                                           \
    for (int g = 0; g < 4; ++g) XW_NXT[g] = *(const unsigned*)(xbase + xoff[g]);\
    const signed char* hr = hb[CUR ^ 1];                                        \
    i32x4 acc[4][2];                                                            \
    {                                                                           \
      i32x4 a0 = *(const i32x4*)(hr + (c & 1) * 288 + q * 16);                  \
      _Pragma("unroll")                                                         \
      for (int g = 0; g < 4; ++g) {                                             \
        __asm__("v_mfma_i32_16x16x64_i8 %0, %1, %2, %3"                         \
                : "=&v"(acc[g][0]) : "v"(a0), "a"(bw[g][0][0]), "v"(zacc));     \
        __asm__("v_mfma_i32_16x16x64_i8 %0, %1, %2, %3"                         \
                : "=&v"(acc[g][1]) : "v"(a0), "a"(bw[g][1][0]), "v"(zacc));     \
      }                                                                         \
    }                                                                           \
    _Pragma("unroll")                                                           \
    for (int ks = 1; ks < 4; ++ks) {                                            \
      i32x4 a = *(const i32x4*)(hr + (c & 1) * 288 + ks * 64 + q * 16);         \
      _Pragma("unroll")                                                         \
      for (int g = 0; g < 4; ++g) {                                             \
        __asm__("v_mfma_i32_16x16x64_i8 %0, %1, %2, %0"                         \
                : "+v"(acc[g][0]) : "v"(a), "a"(bw[g][0][ks]));                 \
        __asm__("v_mfma_i32_16x16x64_i8 %0, %1, %2, %0"                         \
                : "+v"(acc[g][1]) : "v"(a), "a"(bw[g][1][ks]));                 \
      }                                                                         \
    }                                                                           \
    __asm__ volatile("s_nop 7\n\ts_nop 7\n\ts_nop 7");  /* MFMA->VALU hazard */ \
    float a4[4];                                                                \
    _Pragma("unroll")                                                           \
    for (int g = 0; g < 4; ++g) {                                               \
      int e = tt ? (rsel ? acc[g][1][1] : acc[g][1][0])                         \
                 : (rsel ? acc[g][0][1] : acc[g][0][0]);                        \
      unsigned d = XW_CUR[g];                                                   \
      float xv = rsel ? bfhi(d) : bflo(d);                                      \
      a4[g] = (float)e * sc8[g] + xv;                                           \
    }                                                                           \
    float gi = fsig(a4[0]);                                                     \
    float gf = fsig(a4[1]);                                                     \
    float gg = ftanh(a4[2]);                                                    \
    float go = fsig(a4[3]);                                                     \
    cs = gf * cs + gi * gg;                                                     \
    hh = go * ftanh(cs);                                                        \
    int hq = (int)rintf(hh * 127.f);                                            \
    hb[CUR][rsel * 288 + wid * 32 + tt * 16 + c] = (signed char)hq;             \
    xbase += 524288;                                                            \
    __builtin_amdgcn_s_waitcnt(0xC07F);  /* lgkmcnt(0) only, vmcnt in flight */ \
    __builtin_amdgcn_s_barrier();                                               \
  }

  for (int t = 0; t < TT; t += 2) {
    STEP(0, xw0, xw1)
    STEP(1, xw1, xw0)
  }
#undef STEP

  {
    int n = G * 16 + q8 * 2 + rsel;
    int hu = wid * 32 + tt * 16 + c;
    out[(size_t)n * 256 + hu] = hh;
    out[65536 + (size_t)n * 256 + hu] = cs;
  }
}

// ---------- launch ----------
extern "C" void kernel_launch(void* const* d_in, const int* in_sizes, int n_in,
                              void* d_out, int out_size, void* d_ws, size_t ws_size,
                              hipStream_t stream) {
  const float* x   = (const float*)d_in[0];
  const float* wii = (const float*)d_in[1];
  const float* whi = (const float*)d_in[2];
  const float* wif = (const float*)d_in[3];
  const float* whf = (const float*)d_in[4];
  const float* wig = (const float*)d_in[5];
  const float* whg = (const float*)d_in[6];
  const float* wio = (const float*)d_in[7];
  const float* who = (const float*)d_in[8];
  const float* bii = (const float*)d_in[9];
  const float* bhi = (const float*)d_in[10];
  const float* bif = (const float*)d_in[11];
  const float* bhf = (const float*)d_in[12];
  const float* big_ = (const float*)d_in[13];
  const float* bhg = (const float*)d_in[14];
  const float* bio = (const float*)d_in[15];
  const float* bho = (const float*)d_in[16];

  char* ws = (char*)d_ws;
  // (xb region at ws+0 no longer used; offsets kept identical to prior version)
  u16*   Wxb    = (u16*)(ws + 67108864);              //    524,288 B
  signed char* Whq = (signed char*)(ws + 67633152);   //    262,144 B
  float* wscale = (float*)(ws + 67895296);            //      4,096 B
  float* bsum   = (float*)(ws + 67899392);            //      4,096 B
  u16*   xWp    = (u16*)(ws + 67903488);              // 268,435,456 B + 576 KB prefetch pad
  float* out = (float*)d_out;

  prep_w<<<2049, 256, 0, stream>>>(wii, whi, wif, whf, wig, whg, wio, who,
                                   bii, bhi, bif, bhf, big_, bhg, bio, bho,
                                   Wxb, Whq, wscale, bsum);
  gemm_xw<<<1024, 256, 0, stream>>>(x, Wxb, bsum, xWp);
  lstm_rec<<<128, 512, 0, stream>>>(Whq, wscale, xWp, out);
}

// Round 3
// 637.650 us; speedup vs baseline: 1.1685x; 1.0852x over previous
//
#include <hip/hip_runtime.h>
#include <cstdint>

typedef float  f32x4  __attribute__((ext_vector_type(4)));
typedef __bf16 bf16x8 __attribute__((ext_vector_type(8)));
typedef int    i32x4  __attribute__((ext_vector_type(4)));
typedef unsigned short u16;
typedef u16 u16x4 __attribute__((ext_vector_type(4)));

#define TT 512

// ---------- helpers ----------
__device__ __forceinline__ u16 f2bf(float f) {
  unsigned u = __builtin_bit_cast(unsigned, f);
  unsigned r = u + 0x7fffu + ((u >> 16) & 1u);   // RNE
  return (u16)(r >> 16);
}
__device__ __forceinline__ float bflo(unsigned d) { return __builtin_bit_cast(float, d << 16); }
__device__ __forceinline__ float bfhi(unsigned d) { return __builtin_bit_cast(float, d & 0xffff0000u); }
__device__ __forceinline__ float rcpf(float x) { return __builtin_amdgcn_rcpf(x); }
__device__ __forceinline__ float fsig(float x) { return rcpf(1.f + __expf(-x)); }
__device__ __forceinline__ float ftanh(float x) { return 1.f - 2.f * rcpf(1.f + __expf(2.f * x)); }
__device__ __forceinline__ void gload_lds16(const u16* g, u16* l) {
  __builtin_amdgcn_global_load_lds((const __attribute__((address_space(1))) void*)(g),
                                   (__attribute__((address_space(3))) void*)(l), 16, 0, 0);
}

// ---------- prep: Wx -> bf16 transposed; Wh -> i8 per-col quant; bias sum ----------
__global__ __launch_bounds__(256) void prep_w(
    const float* __restrict__ wii, const float* __restrict__ whi,
    const float* __restrict__ wif, const float* __restrict__ whf,
    const float* __restrict__ wig, const float* __restrict__ whg,
    const float* __restrict__ wio, const float* __restrict__ who,
    const float* __restrict__ bii, const float* __restrict__ bhi,
    const float* __restrict__ bif, const float* __restrict__ bhf,
    const float* __restrict__ big_, const float* __restrict__ bhg,
    const float* __restrict__ bio, const float* __restrict__ bho,
    u16* __restrict__ Wxb, signed char* __restrict__ Whq,
    float* __restrict__ wscale, float* __restrict__ bsum) {
  __shared__ float red[256];
  int b = blockIdx.x;
  int tid = threadIdx.x;
  if (b < 1024) {                 // Wxb_t[col][d] = w_x{G}[d][h], col = G*256+h
    const float* wx[4] = {wii, wif, wig, wio};
    int G = b >> 8, h = b & 255;
    Wxb[b * 256 + tid] = f2bf(wx[G][tid * 256 + h]);
  } else if (b < 2048) {          // Whq[col][u] = quant(w_h{G}[u][h]), per-col scale
    const float* wh[4] = {whi, whf, whg, who};
    int cidx = b - 1024;
    int G = cidx >> 8, h = cidx & 255;
    float w = wh[G][tid * 256 + h];
    red[tid] = fabsf(w);
    __syncthreads();
    for (int s = 128; s > 0; s >>= 1) {
      if (tid < s) red[tid] = fmaxf(red[tid], red[tid + s]);
      __syncthreads();
    }
    float mx = red[0];
    float scale = (mx > 0.f) ? mx * (1.f / 127.f) : 1.f;
    float qf = rintf(w / scale);
    qf = fminf(127.f, fmaxf(-127.f, qf));
    Whq[cidx * 256 + tid] = (signed char)(int)qf;
    if (tid == 0) wscale[cidx] = scale * (1.f / 127.f);   // combined w-scale * h-scale
  } else {
    const float* bx[4] = {bii, bif, big_, bio};
    const float* bh[4] = {bhi, bhf, bhg, bho};
    for (int G = 0; G < 4; ++G) bsum[G * 256 + tid] = bx[G][tid] + bh[G][tid];
  }
}

// ---------- fused: producer (xW GEMM, t-ordered) + consumer (recurrence) ----------
// 256 wgs x 512 thr, 83KB LDS => HW-enforced 1 wg/CU, all co-resident.
// p<128: consumer = verified lstm_rec body + per-round acquire-wait.
// p>=128: producer k=p-128, round j computes strip bm=j*128+k (t=64j+k/2);
//   after strip: syncthreads (vmcnt drain) + tid0 RELEASE/AGENT fetch_add
//   (wbl2 flush). Consumer waits rprog[j]==128 before touching round j's xW.
__global__ __launch_bounds__(512, 2) void lstm_fused(
    const float* __restrict__ X, const u16* __restrict__ Bt,
    const float* __restrict__ bias, const signed char* __restrict__ Whq,
    const float* __restrict__ wscale, u16* __restrict__ xWp,
    int* __restrict__ rprog, float* __restrict__ out) {
  __shared__ u16 As[128 * 256];                      // 64 KB (producer)
  __shared__ u16 Bs[2][128 * 32];                    // 16 KB (producer)
  __shared__ __align__(16) signed char hb[2][576];   // consumer
  int p = blockIdx.x;
  int tid = threadIdx.x;

  if (p >= 128) {
    // ================= producer =================
    int k = p - 128;
    int l = tid & 63, w8 = tid >> 6;
    int wm = w8 >> 2, wn = w8 & 3;                   // 2 row-halves x 4 col-quads
    int c = l & 15, q = l >> 4;
    int sw = (c & 7) << 4;
    int rowbase[4];
#pragma unroll
    for (int mt = 0; mt < 4; ++mt) rowbase[mt] = (wm * 64 + mt * 16 + c) * 512;

    for (int j = 0; j < 8; ++j) {
      int bm = j * 128 + k;
      // stage B(bn=0,ko=0) early: 512 lanes x 16B = full 8KB in one shot
      {
        int trow = tid >> 2, ch = tid & 3;
        gload_lds16(Bt + (size_t)trow * 256 + ch * 8, &Bs[0][0] + tid * 8);
      }
      // stage A strip: 128 rows x 256 k, f32 -> bf16, XOR-swizzled
#pragma unroll 4
      for (int jj = 0; jj < 16; ++jj) {
        int row_l = jj * 8 + w8;                     // wave reads one row contiguously
        int d = l * 4;
        int r = bm * 128 + row_l;
        int t = r >> 8, n = r & 255;
        const float4 v = *(const float4*)(X + ((size_t)n * 512 + t) * 256 + d);
        u16x4 pk;
        pk[0] = f2bf(v.x); pk[1] = f2bf(v.y); pk[2] = f2bf(v.z); pk[3] = f2bf(v.w);
        int ba = (row_l * 512 + l * 8) ^ ((row_l & 7) << 4);
        *(u16x4*)((char*)As + ba) = pk;
      }
      __syncthreads();

      f32x4 acc[4][2];
#pragma unroll
      for (int i = 0; i < 4; ++i)
#pragma unroll
        for (int jn = 0; jn < 2; ++jn) acc[i][jn] = (f32x4){0.f, 0.f, 0.f, 0.f};

      for (int bn = 0; bn < 8; ++bn) {
#pragma unroll
        for (int ko = 0; ko < 8; ++ko) {
          int sn = bn * 8 + ko + 1;                  // stage next (bn,ko) before compute
          if (sn < 64) {
            int bnn = sn >> 3, kon = sn & 7;
            const u16* Bb = Bt + (size_t)(bnn * 128) * 256 + kon * 32;
            int trow = tid >> 2, ch = tid & 3;
            gload_lds16(Bb + (size_t)trow * 256 + ch * 8, &Bs[(ko + 1) & 1][0] + tid * 8);
          }
          bf16x8 af[4], bfr[2];
          const u16* bp = &Bs[ko & 1][0];
          int koff = (ko * 64 + q * 16) ^ sw;        // full XOR involution, matches write
#pragma unroll
          for (int mt = 0; mt < 4; ++mt)
            af[mt] = *(const bf16x8*)((const char*)As + rowbase[mt] + koff);
#pragma unroll
          for (int nt = 0; nt < 2; ++nt)
            bfr[nt] = *(const bf16x8*)(bp + (wn * 32 + nt * 16 + c) * 32 + q * 8);
#pragma unroll
          for (int mt = 0; mt < 4; ++mt)
#pragma unroll
            for (int nt = 0; nt < 2; ++nt)
              acc[mt][nt] = __builtin_amdgcn_mfma_f32_16x16x32_bf16(af[mt], bfr[nt], acc[mt][nt], 0, 0, 0);
          __syncthreads();           // vmcnt(0): next B staged; lgkm: reads done
        }
        // epilogue for this bn (identical packing to verified kernel)
#pragma unroll
        for (int mt = 0; mt < 4; ++mt) {
          int tm = bm * 8 + wm * 4 + mt;
#pragma unroll
          for (int nt = 0; nt < 2; ++nt) {
            int tn = bn * 8 + wn * 2 + nt;
            float bv = bias[tn * 16 + c];
            u16x4 pk;
#pragma unroll
            for (int r = 0; r < 4; ++r) pk[r] = f2bf(acc[mt][nt][r] + bv);
            *reinterpret_cast<u16x4*>(xWp + ((size_t)(tm * 64 + tn) * 256 + l * 4)) = pk;
            acc[mt][nt] = (f32x4){0.f, 0.f, 0.f, 0.f};
          }
        }
      }
      __syncthreads();               // drain epilogue stores (vmcnt(0)) wg-wide
      if (tid == 0)
        __hip_atomic_fetch_add(&rprog[j], 1, __ATOMIC_RELEASE, __HIP_MEMORY_SCOPE_AGENT);
    }
    return;
  }

  // ================= consumer (verified lstm_rec + round waits) =================
  int xcd = p & 7, q8 = (p >> 3) & 7, tsel = p >> 6;
  int G = xcd * 2 + tsel;        // 16-row tile id; 8 co-XCD sharers
  int wid = tid >> 6, l = tid & 63;
  int c = l & 15, q = (l >> 4) & 3;
  int tt = q >> 1, rsel = q & 1;

  for (int i = tid; i < 288; i += 512) ((int*)hb)[i] = 0;

  // Wh i8 fragments: [gate][tt-tile][kstep] -> forced into AGPRs by asm "a" use
  i32x4 bw[4][2][4];
#pragma unroll
  for (int g = 0; g < 4; ++g)
#pragma unroll
    for (int ttl = 0; ttl < 2; ++ttl) {
      int col = g * 256 + wid * 32 + ttl * 16 + c;
#pragma unroll
      for (int ks = 0; ks < 4; ++ks)
        bw[g][ttl][ks] = *reinterpret_cast<const i32x4*>(Whq + (size_t)col * 256 + ks * 64 + q * 16);
    }
  float sc8[4];
#pragma unroll
  for (int g = 0; g < 4; ++g) sc8[g] = wscale[g * 256 + wid * 32 + tt * 16 + c];

  // xW: tile tm = t*16 + G; this wg's rows are regs {2*(q8&1), +1} of quad q8>>1
  const char* xbase = (const char*)xWp + (size_t)G * 32768;
  int xoff[4];
#pragma unroll
  for (int g = 0; g < 4; ++g) {
    int tn = g * 16 + wid * 2 + tt;
    xoff[g] = tn * 512 + (((q8 >> 1) * 16 + c) * 8) + (q8 & 1) * 4;
  }

  // wait for round 0 (t=0..63) before touching xWp
  if (tid == 0) {
    while (__hip_atomic_load(&rprog[0], __ATOMIC_RELAXED, __HIP_MEMORY_SCOPE_AGENT) < 128)
      __builtin_amdgcn_s_sleep(8);
    (void)__hip_atomic_load(&rprog[0], __ATOMIC_ACQUIRE, __HIP_MEMORY_SCOPE_AGENT);
  }
  __syncthreads();

  unsigned xw0[4], xw1[4];
#pragma unroll
  for (int g = 0; g < 4; ++g) xw0[g] = *(const unsigned*)(xbase + xoff[g]);   // t=0
  xbase += 524288;   // -> t=1

  i32x4 zacc = (i32x4){0, 0, 0, 0};
  float cs = 0.f, hh = 0.f;
  __syncthreads();

#define STEP(CUR, XW_CUR, XW_NXT)                                               \
  {                                                                             \
    _Pragma("unroll")                                                           \
    for (int g = 0; g < 4; ++g) XW_NXT[g] = *(const unsigned*)(xbase + xoff[g]);\
    const signed char* hr = hb[CUR ^ 1];                                        \
    i32x4 acc[4][2];                                                            \
    {                                                                           \
      i32x4 a0 = *(const i32x4*)(hr + (c & 1) * 288 + q * 16);                  \
      _Pragma("unroll")                                                         \
      for (int g = 0; g < 4; ++g) {                                             \
        __asm__("v_mfma_i32_16x16x64_i8 %0, %1, %2, %3"                         \
                : "=&v"(acc[g][0]) : "v"(a0), "a"(bw[g][0][0]), "v"(zacc));     \
        __asm__("v_mfma_i32_16x16x64_i8 %0, %1, %2, %3"                         \
                : "=&v"(acc[g][1]) : "v"(a0), "a"(bw[g][1][0]), "v"(zacc));     \
      }                                                                         \
    }                                                                           \
    _Pragma("unroll")                                                           \
    for (int ks = 1; ks < 4; ++ks) {                                            \
      i32x4 a = *(const i32x4*)(hr + (c & 1) * 288 + ks * 64 + q * 16);         \
      _Pragma("unroll")                                                         \
      for (int g = 0; g < 4; ++g) {                                             \
        __asm__("v_mfma_i32_16x16x64_i8 %0, %1, %2, %0"                         \
                : "+v"(acc[g][0]) : "v"(a), "a"(bw[g][0][ks]));                 \
        __asm__("v_mfma_i32_16x16x64_i8 %0, %1, %2, %0"                         \
                : "+v"(acc[g][1]) : "v"(a), "a"(bw[g][1][ks]));                 \
      }                                                                         \
    }                                                                           \
    __asm__ volatile("s_nop 7\n\ts_nop 7\n\ts_nop 7");  /* MFMA->VALU hazard */ \
    float a4[4];                                                                \
    _Pragma("unroll")                                                           \
    for (int g = 0; g < 4; ++g) {                                               \
      int e = tt ? (rsel ? acc[g][1][1] : acc[g][1][0])                         \
                 : (rsel ? acc[g][0][1] : acc[g][0][0]);                        \
      unsigned d = XW_CUR[g];                                                   \
      float xv = rsel ? bfhi(d) : bflo(d);                                      \
      a4[g] = (float)e * sc8[g] + xv;                                           \
    }                                                                           \
    float gi = fsig(a4[0]);                                                     \
    float gf = fsig(a4[1]);                                                     \
    float gg = ftanh(a4[2]);                                                    \
    float go = fsig(a4[3]);                                                     \
    cs = gf * cs + gi * gg;                                                     \
    hh = go * ftanh(cs);                                                        \
    int hq = (int)rintf(hh * 127.f);                                            \
    hb[CUR][rsel * 288 + wid * 32 + tt * 16 + c] = (signed char)hq;             \
    xbase += 524288;                                                            \
    __builtin_amdgcn_s_waitcnt(0xC07F);  /* lgkmcnt(0) only, vmcnt in flight */ \
    __builtin_amdgcn_s_barrier();                                               \
  }

  for (int t = 0; t < TT; t += 2) {
    STEP(0, xw0, xw1)
    if (((t + 2) & 63) == 0 && (t + 2) < TT) {
      // next STEP prefetches t+2 (first step of round (t+2)/64): wait for it
      int j = (t + 2) >> 6;
      if (tid == 0) {
        while (__hip_atomic_load(&rprog[j], __ATOMIC_RELAXED, __HIP_MEMORY_SCOPE_AGENT) < 128)
          __builtin_amdgcn_s_sleep(8);
        (void)__hip_atomic_load(&rprog[j], __ATOMIC_ACQUIRE, __HIP_MEMORY_SCOPE_AGENT);
      }
      __syncthreads();
    }
    STEP(1, xw1, xw0)
  }
#undef STEP

  {
    int n = G * 16 + q8 * 2 + rsel;
    int hu = wid * 32 + tt * 16 + c;
    out[(size_t)n * 256 + hu] = hh;
    out[65536 + (size_t)n * 256 + hu] = cs;
  }
}

// ---------- launch ----------
extern "C" void kernel_launch(void* const* d_in, const int* in_sizes, int n_in,
                              void* d_out, int out_size, void* d_ws, size_t ws_size,
                              hipStream_t stream) {
  const float* x   = (const float*)d_in[0];
  const float* wii = (const float*)d_in[1];
  const float* whi = (const float*)d_in[2];
  const float* wif = (const float*)d_in[3];
  const float* whf = (const float*)d_in[4];
  const float* wig = (const float*)d_in[5];
  const float* whg = (const float*)d_in[6];
  const float* wio = (const float*)d_in[7];
  const float* who = (const float*)d_in[8];
  const float* bii = (const float*)d_in[9];
  const float* bhi = (const float*)d_in[10];
  const float* bif = (const float*)d_in[11];
  const float* bhf = (const float*)d_in[12];
  const float* big_ = (const float*)d_in[13];
  const float* bhg = (const float*)d_in[14];
  const float* bio = (const float*)d_in[15];
  const float* bho = (const float*)d_in[16];

  char* ws = (char*)d_ws;
  int*   rprog  = (int*)(ws);                         // 64 B (zeroed per launch)
  u16*   Wxb    = (u16*)(ws + 67108864);              //    524,288 B
  signed char* Whq = (signed char*)(ws + 67633152);   //    262,144 B
  float* wscale = (float*)(ws + 67895296);            //      4,096 B
  float* bsum   = (float*)(ws + 67899392);            //      4,096 B
  u16*   xWp    = (u16*)(ws + 67903488);              // 268,435,456 B + 576 KB prefetch pad
  float* out = (float*)d_out;

  hipMemsetAsync(rprog, 0, 64, stream);
  prep_w<<<2049, 256, 0, stream>>>(wii, whi, wif, whf, wig, whg, wio, who,
                                   bii, bhi, bif, bhf, big_, bhg, bio, bho,
                                   Wxb, Whq, wscale, bsum);
  lstm_fused<<<256, 512, 0, stream>>>(x, Wxb, bsum, Whq, wscale, xWp, rprog, out);
}

// Round 4
// 614.888 us; speedup vs baseline: 1.2118x; 1.0370x over previous
//
#include <hip/hip_runtime.h>
#include <cstdint>

typedef float  f32x4  __attribute__((ext_vector_type(4)));
typedef __bf16 bf16x8 __attribute__((ext_vector_type(8)));
typedef int    i32x4  __attribute__((ext_vector_type(4)));
typedef unsigned short u16;
typedef u16 u16x4 __attribute__((ext_vector_type(4)));

#define TT 512

// ---------- helpers ----------
__device__ __forceinline__ u16 f2bf(float f) {
  unsigned u = __builtin_bit_cast(unsigned, f);
  unsigned r = u + 0x7fffu + ((u >> 16) & 1u);   // RNE
  return (u16)(r >> 16);
}
__device__ __forceinline__ float bflo(unsigned d) { return __builtin_bit_cast(float, d << 16); }
__device__ __forceinline__ float bfhi(unsigned d) { return __builtin_bit_cast(float, d & 0xffff0000u); }
__device__ __forceinline__ float rcpf(float x) { return __builtin_amdgcn_rcpf(x); }
__device__ __forceinline__ float fsig(float x) { return rcpf(1.f + __expf(-x)); }
__device__ __forceinline__ float ftanh(float x) { return 1.f - 2.f * rcpf(1.f + __expf(2.f * x)); }
__device__ __forceinline__ void gload_lds16(const u16* g, u16* l) {
  __builtin_amdgcn_global_load_lds((const __attribute__((address_space(1))) void*)(g),
                                   (__attribute__((address_space(3))) void*)(l), 16, 0, 0);
}

// ---------- prep: Wx -> bf16 transposed; Wh -> i8 per-col quant; bias sum ----------
__global__ __launch_bounds__(256) void prep_w(
    const float* __restrict__ wii, const float* __restrict__ whi,
    const float* __restrict__ wif, const float* __restrict__ whf,
    const float* __restrict__ wig, const float* __restrict__ whg,
    const float* __restrict__ wio, const float* __restrict__ who,
    const float* __restrict__ bii, const float* __restrict__ bhi,
    const float* __restrict__ bif, const float* __restrict__ bhf,
    const float* __restrict__ big_, const float* __restrict__ bhg,
    const float* __restrict__ bio, const float* __restrict__ bho,
    u16* __restrict__ Wxb, signed char* __restrict__ Whq,
    float* __restrict__ wscale, float* __restrict__ bsum) {
  __shared__ float red[256];
  int b = blockIdx.x;
  int tid = threadIdx.x;
  if (b < 1024) {                 // Wxb_t[col][d] = w_x{G}[d][h], col = G*256+h
    const float* wx[4] = {wii, wif, wig, wio};
    int G = b >> 8, h = b & 255;
    Wxb[b * 256 + tid] = f2bf(wx[G][tid * 256 + h]);
  } else if (b < 2048) {          // Whq[col][u] = quant(w_h{G}[u][h]), per-col scale
    const float* wh[4] = {whi, whf, whg, who};
    int cidx = b - 1024;
    int G = cidx >> 8, h = cidx & 255;
    float w = wh[G][tid * 256 + h];
    red[tid] = fabsf(w);
    __syncthreads();
    for (int s = 128; s > 0; s >>= 1) {
      if (tid < s) red[tid] = fmaxf(red[tid], red[tid + s]);
      __syncthreads();
    }
    float mx = red[0];
    float scale = (mx > 0.f) ? mx * (1.f / 127.f) : 1.f;
    float qf = rintf(w / scale);
    qf = fminf(127.f, fmaxf(-127.f, qf));
    Whq[cidx * 256 + tid] = (signed char)(int)qf;
    if (tid == 0) wscale[cidx] = scale * (1.f / 127.f);   // combined w-scale * h-scale
  } else {
    const float* bx[4] = {bii, bif, big_, bio};
    const float* bh[4] = {bhi, bhf, bhg, bho};
    for (int G = 0; G < 4; ++G) bsum[G * 256 + tid] = bx[G][tid] + bh[G][tid];
  }
}

// ---------- fused: producer (xW GEMM, t-ordered) + consumer (recurrence) ----------
// 256 wgs x 512 thr, ~130KB LDS => 1 wg/CU, all co-resident.
// p<128: consumer = verified lstm_rec body + per-round acquire-wait (unchanged).
// p>=128: producer k=p-128, round j computes strip bm=j*128+k.
// Producer rework vs round 3 (which paced the kernel at ~65us/strip):
//  - B staged per-bn as a full 64KB panel [col][K] into Bp; ko-loop is pure
//    LDS->MFMA (no barriers, no vmcnt drains). 16 barriers/strip, not 64.
//  - B panel XOR-swizzled byte^=(col&7)<<4 via pre-swizzled GLOBAL source
//    (linear gload_lds dest) + swizzled read: kills the 8-way bank conflict
//    (12.6M conflict-cycles in round 3). col==c (mod 8) => same koff as A.
__global__ __launch_bounds__(512, 2) void lstm_fused(
    const float* __restrict__ X, const u16* __restrict__ Bt,
    const float* __restrict__ bias, const signed char* __restrict__ Whq,
    const float* __restrict__ wscale, u16* __restrict__ xWp,
    int* __restrict__ rprog, float* __restrict__ out) {
  __shared__ u16 As[128 * 256];                      // 64 KB A strip (swizzled)
  __shared__ u16 Bp[128 * 256];                      // 64 KB B panel (swizzled)
  __shared__ __align__(16) signed char hb[2][576];   // consumer
  int p = blockIdx.x;
  int tid = threadIdx.x;

  if (p >= 128) {
    // ================= producer =================
    int k = p - 128;
    int l = tid & 63, w8 = tid >> 6;
    int wm = w8 >> 2, wn = w8 & 3;                   // 2 row-halves x 4 col-quads
    int c = l & 15, q = l >> 4;
    int sw = (c & 7) << 4;
    int rowbase[4];
#pragma unroll
    for (int mt = 0; mt < 4; ++mt) rowbase[mt] = (wm * 64 + mt * 16 + c) * 512;

    // stage one 64KB B panel (bn): LDS[i*16B] <- Bt[col=bn*128+i/32][swz]
    // src u16 = (bn*128+cl)*256 + ((wk*8) ^ ((cl&7)<<3)); dst = Bp + i*8 u16
#define STAGE_B(BN)                                                             \
    {                                                                           \
      _Pragma("unroll")                                                         \
      for (int s = 0; s < 8; ++s) {                                             \
        int i = s * 512 + tid;                                                  \
        int cl = i >> 5, wk = i & 31;                                           \
        gload_lds16(Bt + (size_t)((BN) * 128 + cl) * 256 +                      \
                        ((wk * 8) ^ ((cl & 7) << 3)),                           \
                    Bp + i * 8);                                                \
      }                                                                         \
    }

    for (int j = 0; j < 8; ++j) {
      int bm = j * 128 + k;
      __syncthreads();                               // As/Bp free (prev strip read)
      STAGE_B(0)
      // stage A strip: 128 rows x 256 k, f32 -> bf16, XOR-swizzled (hides B latency)
#pragma unroll 4
      for (int jj = 0; jj < 16; ++jj) {
        int row_l = jj * 8 + w8;                     // wave reads one row contiguously
        int d = l * 4;
        int r = bm * 128 + row_l;
        int t = r >> 8, n = r & 255;
        const float4 v = *(const float4*)(X + ((size_t)n * 512 + t) * 256 + d);
        u16x4 pk;
        pk[0] = f2bf(v.x); pk[1] = f2bf(v.y); pk[2] = f2bf(v.z); pk[3] = f2bf(v.w);
        int ba = (row_l * 512 + l * 8) ^ ((row_l & 7) << 4);
        *(u16x4*)((char*)As + ba) = pk;
      }
      __syncthreads();                               // A (lgkm) + B panel (vmcnt) ready

      f32x4 acc[4][2];
#pragma unroll
      for (int i = 0; i < 4; ++i)
#pragma unroll
        for (int jn = 0; jn < 2; ++jn) acc[i][jn] = (f32x4){0.f, 0.f, 0.f, 0.f};

      for (int bn = 0; bn < 8; ++bn) {
#pragma unroll
        for (int ko = 0; ko < 8; ++ko) {             // pure LDS->MFMA, no barriers
          bf16x8 af[4], bfr[2];
          int koff = (ko * 64 + q * 16) ^ sw;        // shared A/B involution
#pragma unroll
          for (int mt = 0; mt < 4; ++mt)
            af[mt] = *(const bf16x8*)((const char*)As + rowbase[mt] + koff);
#pragma unroll
          for (int nt = 0; nt < 2; ++nt)
            bfr[nt] = *(const bf16x8*)((const char*)Bp + (size_t)(wn * 32 + nt * 16 + c) * 512 + koff);
#pragma unroll
          for (int mt = 0; mt < 4; ++mt)
#pragma unroll
            for (int nt = 0; nt < 2; ++nt)
              acc[mt][nt] = __builtin_amdgcn_mfma_f32_16x16x32_bf16(af[mt], bfr[nt], acc[mt][nt], 0, 0, 0);
        }
        // epilogue for this bn (identical packing to verified kernel)
#pragma unroll
        for (int mt = 0; mt < 4; ++mt) {
          int tm = bm * 8 + wm * 4 + mt;
#pragma unroll
          for (int nt = 0; nt < 2; ++nt) {
            int tn = bn * 8 + wn * 2 + nt;
            float bv = bias[tn * 16 + c];
            u16x4 pk;
#pragma unroll
            for (int r = 0; r < 4; ++r) pk[r] = f2bf(acc[mt][nt][r] + bv);
            *reinterpret_cast<u16x4*>(xWp + ((size_t)(tm * 64 + tn) * 256 + l * 4)) = pk;
            acc[mt][nt] = (f32x4){0.f, 0.f, 0.f, 0.f};
          }
        }
        if (bn < 7) {
          __syncthreads();                           // all waves done reading Bp
          STAGE_B(bn + 1)
          __syncthreads();                           // panel staged (+ stores drained)
        }
      }
      __syncthreads();                               // drain epilogue stores wg-wide
      if (tid == 0)
        __hip_atomic_fetch_add(&rprog[j], 1, __ATOMIC_RELEASE, __HIP_MEMORY_SCOPE_AGENT);
    }
#undef STAGE_B
    return;
  }

  // ================= consumer (verified lstm_rec + round waits) =================
  int xcd = p & 7, q8 = (p >> 3) & 7, tsel = p >> 6;
  int G = xcd * 2 + tsel;        // 16-row tile id; 8 co-XCD sharers
  int wid = tid >> 6, l = tid & 63;
  int c = l & 15, q = (l >> 4) & 3;
  int tt = q >> 1, rsel = q & 1;

  for (int i = tid; i < 288; i += 512) ((int*)hb)[i] = 0;

  // Wh i8 fragments: [gate][tt-tile][kstep] -> forced into AGPRs by asm "a" use
  i32x4 bw[4][2][4];
#pragma unroll
  for (int g = 0; g < 4; ++g)
#pragma unroll
    for (int ttl = 0; ttl < 2; ++ttl) {
      int col = g * 256 + wid * 32 + ttl * 16 + c;
#pragma unroll
      for (int ks = 0; ks < 4; ++ks)
        bw[g][ttl][ks] = *reinterpret_cast<const i32x4*>(Whq + (size_t)col * 256 + ks * 64 + q * 16);
    }
  float sc8[4];
#pragma unroll
  for (int g = 0; g < 4; ++g) sc8[g] = wscale[g * 256 + wid * 32 + tt * 16 + c];

  // xW: tile tm = t*16 + G; this wg's rows are regs {2*(q8&1), +1} of quad q8>>1
  const char* xbase = (const char*)xWp + (size_t)G * 32768;
  int xoff[4];
#pragma unroll
  for (int g = 0; g < 4; ++g) {
    int tn = g * 16 + wid * 2 + tt;
    xoff[g] = tn * 512 + (((q8 >> 1) * 16 + c) * 8) + (q8 & 1) * 4;
  }

  // wait for round 0 (t=0..63) before touching xWp
  if (tid == 0) {
    while (__hip_atomic_load(&rprog[0], __ATOMIC_RELAXED, __HIP_MEMORY_SCOPE_AGENT) < 128)
      __builtin_amdgcn_s_sleep(8);
    (void)__hip_atomic_load(&rprog[0], __ATOMIC_ACQUIRE, __HIP_MEMORY_SCOPE_AGENT);
  }
  __syncthreads();

  unsigned xw0[4], xw1[4];
#pragma unroll
  for (int g = 0; g < 4; ++g) xw0[g] = *(const unsigned*)(xbase + xoff[g]);   // t=0
  xbase += 524288;   // -> t=1

  i32x4 zacc = (i32x4){0, 0, 0, 0};
  float cs = 0.f, hh = 0.f;
  __syncthreads();

#define STEP(CUR, XW_CUR, XW_NXT)                                               \
  {                                                                             \
    _Pragma("unroll")                                                           \
    for (int g = 0; g < 4; ++g) XW_NXT[g] = *(const unsigned*)(xbase + xoff[g]);\
    const signed char* hr = hb[CUR ^ 1];                                        \
    i32x4 acc[4][2];                                                            \
    {                                                                           \
      i32x4 a0 = *(const i32x4*)(hr + (c & 1) * 288 + q * 16);                  \
      _Pragma("unroll")                                                         \
      for (int g = 0; g < 4; ++g) {                                             \
        __asm__("v_mfma_i32_16x16x64_i8 %0, %1, %2, %3"                         \
                : "=&v"(acc[g][0]) : "v"(a0), "a"(bw[g][0][0]), "v"(zacc));     \
        __asm__("v_mfma_i32_16x16x64_i8 %0, %1, %2, %3"                         \
                : "=&v"(acc[g][1]) : "v"(a0), "a"(bw[g][1][0]), "v"(zacc));     \
      }                                                                         \
    }                                                                           \
    _Pragma("unroll")                                                           \
    for (int ks = 1; ks < 4; ++ks) {                                            \
      i32x4 a = *(const i32x4*)(hr + (c & 1) * 288 + ks * 64 + q * 16);         \
      _Pragma("unroll")                                                         \
      for (int g = 0; g < 4; ++g) {                                             \
        __asm__("v_mfma_i32_16x16x64_i8 %0, %1, %2, %0"                         \
                : "+v"(acc[g][0]) : "v"(a), "a"(bw[g][0][ks]));                 \
        __asm__("v_mfma_i32_16x16x64_i8 %0, %1, %2, %0"                         \
                : "+v"(acc[g][1]) : "v"(a), "a"(bw[g][1][ks]));                 \
      }                                                                         \
    }                                                                           \
    __asm__ volatile("s_nop 7\n\ts_nop 7\n\ts_nop 7");  /* MFMA->VALU hazard */ \
    float a4[4];                                                                \
    _Pragma("unroll")                                                           \
    for (int g = 0; g < 4; ++g) {                                               \
      int e = tt ? (rsel ? acc[g][1][1] : acc[g][1][0])                         \
                 : (rsel ? acc[g][0][1] : acc[g][0][0]);                        \
      unsigned d = XW_CUR[g];                                                   \
      float xv = rsel ? bfhi(d) : bflo(d);                                      \
      a4[g] = (float)e * sc8[g] + xv;                                           \
    }                                                                           \
    float gi = fsig(a4[0]);                                                     \
    float gf = fsig(a4[1]);                                                     \
    float gg = ftanh(a4[2]);                                                    \
    float go = fsig(a4[3]);                                                     \
    cs = gf * cs + gi * gg;                                                     \
    hh = go * ftanh(cs);                                                        \
    int hq = (int)rintf(hh * 127.f);                                            \
    hb[CUR][rsel * 288 + wid * 32 + tt * 16 + c] = (signed char)hq;             \
    xbase += 524288;                                                            \
    __builtin_amdgcn_s_waitcnt(0xC07F);  /* lgkmcnt(0) only, vmcnt in flight */ \
    __builtin_amdgcn_s_barrier();                                               \
  }

  for (int t = 0; t < TT; t += 2) {
    STEP(0, xw0, xw1)
    if (((t + 2) & 63) == 0 && (t + 2) < TT) {
      // next STEP prefetches t+2 (first step of round (t+2)/64): wait for it
      int j = (t + 2) >> 6;
      if (tid == 0) {
        while (__hip_atomic_load(&rprog[j], __ATOMIC_RELAXED, __HIP_MEMORY_SCOPE_AGENT) < 128)
          __builtin_amdgcn_s_sleep(8);
        (void)__hip_atomic_load(&rprog[j], __ATOMIC_ACQUIRE, __HIP_MEMORY_SCOPE_AGENT);
      }
      __syncthreads();
    }
    STEP(1, xw1, xw0)
  }
#undef STEP

  {
    int n = G * 16 + q8 * 2 + rsel;
    int hu = wid * 32 + tt * 16 + c;
    out[(size_t)n * 256 + hu] = hh;
    out[65536 + (size_t)n * 256 + hu] = cs;
  }
}

// ---------- launch ----------
extern "C" void kernel_launch(void* const* d_in, const int* in_sizes, int n_in,
                              void* d_out, int out_size, void* d_ws, size_t ws_size,
                              hipStream_t stream) {
  const float* x   = (const float*)d_in[0];
  const float* wii = (const float*)d_in[1];
  const float* whi = (const float*)d_in[2];
  const float* wif = (const float*)d_in[3];
  const float* whf = (const float*)d_in[4];
  const float* wig = (const float*)d_in[5];
  const float* whg = (const float*)d_in[6];
  const float* wio = (const float*)d_in[7];
  const float* who = (const float*)d_in[8];
  const float* bii = (const float*)d_in[9];
  const float* bhi = (const float*)d_in[10];
  const float* bif = (const float*)d_in[11];
  const float* bhf = (const float*)d_in[12];
  const float* big_ = (const float*)d_in[13];
  const float* bhg = (const float*)d_in[14];
  const float* bio = (const float*)d_in[15];
  const float* bho = (const float*)d_in[16];

  char* ws = (char*)d_ws;
  int*   rprog  = (int*)(ws);                         // 64 B (zeroed per launch)
  u16*   Wxb    = (u16*)(ws + 67108864);              //    524,288 B
  signed char* Whq = (signed char*)(ws + 67633152);   //    262,144 B
  float* wscale = (float*)(ws + 67895296);            //      4,096 B
  float* bsum   = (float*)(ws + 67899392);            //      4,096 B
  u16*   xWp    = (u16*)(ws + 67903488);              // 268,435,456 B + 576 KB prefetch pad
  float* out = (float*)d_out;

  hipMemsetAsync(rprog, 0, 64, stream);
  prep_w<<<2049, 256, 0, stream>>>(wii, whi, wif, whf, wig, whg, wio, who,
                                   bii, bhi, bif, bhf, big_, bhg, bio, bho,
                                   Wxb, Whq, wscale, bsum);
  lstm_fused<<<256, 512, 0, stream>>>(x, Wxb, bsum, Whq, wscale, xWp, rprog, out);
}